// Round 9
// baseline (109.687 us; speedup 1.0000x reference)
//
#include <hip/hip_runtime.h>
#include <math.h>

// n=16384 Gaussian points in 3D. Exact 12-NN (incl self) per point:
//   out[i] = b + ( (W·p_i)·(1 + 11/sqrt(2)) + 0.5 * sum_{11NN} W·|p_i - p_j| ) / 12
//
// R23: R22 flipped the regime to VALU-issue-bound (VALUBusy 80%). Cut
// instructions: selection needs only d2, not (d2,w) pairs.
//   - pass 1 (seed 768 + extent tails): per-lane top-4 of d2 via med3 chain
//     (4 ops/cand, replaces 20-op paired ins4) + eviction watermark
//     ev = min(ev, max(d2, dd[3])).
//   - tau = 12-round wave-min knockout over dd (exact 12th of scanned set;
//     scanned ⊇ extent ⊇ true 12-NN).
//   - watermark violated (any lane ev <= tau, rare) -> rebuild exact tau via
//     full-extent 12-deep med3 chain + knockout.
//   - ONE unified rescan over the extent accumulates acc = sum (d2<=tau)?w:0
//     (w computed only here; same accumulate semantics the fallback always
//     used). ~13 L2-hot batches, latency covered by 46% occupancy TLP.
//   - dropped cs[12] pinned preload + sched_barrier (register churn at
//     VGPR=32; compiler pipelines fine without it per R22 counters).
// Sort unchanged (R18: one self-sufficient plain dispatch, <15 µs).

#define NBINS  2048
#define PARTS  16
#define CMIN_  (-6.0f)
#define INVBW_ ((float)NBINS / 12.0f)
#define BLOCK  256
#define WPB    4
#define SEED   768
#define KK     12
#define CD     4
#define BIG    3.0e38f

__device__ __forceinline__ int bin_of(float x) {
  int b = (int)((x - CMIN_) * INVBW_);
  b = b < 0 ? 0 : b;
  b = b > NBINS - 1 ? NBINS - 1 : b;
  return b;
}

__device__ __forceinline__ float wave_min(float v) {
#pragma unroll
  for (int o = 1; o < 64; o <<= 1) v = fminf(v, __shfl_xor(v, o));
  return v;
}

// ---------------- K1: self-sufficient fused sort (grid = 3*PARTS, plain) ----
__global__ __launch_bounds__(1024)
void sort_kernel(const float* __restrict__ p, int* __restrict__ c_all,
                 float4* __restrict__ s_all, int n) {
  __shared__ int h_all[NBINS];   // full per-axis histogram
  __shared__ int h_pre[NBINS];   // hist of indices < myStart; later: cursors
  __shared__ int wsum[16];
  const int tid  = threadIdx.x;
  const int dim  = blockIdx.x / PARTS;
  const int part = blockIdx.x % PARTS;
  const int chunk   = (n + PARTS - 1) / PARTS;
  const int myStart = part * chunk;
  const int myEnd   = min(myStart + chunk, n);

  h_all[tid] = 0; h_all[tid + 1024] = 0;
  h_pre[tid] = 0; h_pre[tid + 1024] = 0;
  __syncthreads();

  for (int i = tid; i < n; i += 1024) {
    const int b = bin_of(p[3 * i + dim]);
    atomicAdd(&h_all[b], 1);
    if (i < myStart) atomicAdd(&h_pre[b], 1);   // wave-uniform predicate
  }
  __syncthreads();

  const int a = h_all[2 * tid], b = h_all[2 * tid + 1];
  const int v = a + b;
  const int lane = tid & 63, wid = tid >> 6;     // 16 waves
  int incl = v;
#pragma unroll
  for (int o = 1; o < 64; o <<= 1) {
    const int t = __shfl_up(incl, o);
    if (lane >= o) incl += t;
  }
  if (lane == 63) wsum[wid] = incl;
  __syncthreads();
  int woff = 0;
  for (int wI = 0; wI < wid; ++wI) woff += wsum[wI];   // broadcast reads
  const int excl = woff + incl - v;                    // start of bin 2*tid

  if (part == 0) {
    int* __restrict__ cursor = c_all + (size_t)dim * NBINS;
    cursor[2 * tid]     = excl + a;
    cursor[2 * tid + 1] = excl + a + b;
  }

  const int c0 = excl + h_pre[2 * tid];
  const int c1 = excl + a + h_pre[2 * tid + 1];
  __syncthreads();
  h_pre[2 * tid]     = c0;
  h_pre[2 * tid + 1] = c1;
  __syncthreads();

  float4* __restrict__ sorted = s_all + (size_t)dim * n;
  for (int i = myStart + tid; i < myEnd; i += 1024) {
    const float x = p[3 * i], y = p[3 * i + 1], z = p[3 * i + 2];
    const float c = (dim == 0) ? x : (dim == 1) ? y : z;
    const int pos = atomicAdd(&h_pre[bin_of(c)], 1);
    sorted[pos] = make_float4(x, y, z, __int_as_float(i));
  }
}

// ---------------- K2: query (one wave per query, d2-select + rescan) --------
__global__ __launch_bounds__(BLOCK, 1)
void query_kernel(const float4* __restrict__ sx, const float4* __restrict__ sy,
                  const float4* __restrict__ sz, const int* __restrict__ cx,
                  const int* __restrict__ cy, const int* __restrict__ cz,
                  const float* __restrict__ W, const float* __restrict__ bias,
                  float* __restrict__ out, int n) {
  const int lane = threadIdx.x & 63;
  const int wv   = threadIdx.x >> 6;
  const int t    = wv * (n >> 2) + blockIdx.x;     // quartile interleave
  const float W0 = W[0], W1 = W[1], W2 = W[2];
  const float bb = bias[0];

  const float4 me = sx[t];                          // enumerate via x-sorted
  const float xi = me.x, yi = me.y, zi = me.z;
  const int orig = __float_as_int(me.w);

  // ---- choose axis with max |coord| (wave-uniform) ----
  const float ax = fabsf(xi), ay = fabsf(yi), az = fabsf(zi);
  const float4* sv; const int* cur; float cq;
  if (ay >= ax && ay >= az)      { sv = sy; cur = cy; cq = yi; }
  else if (az >= ax && az >= ay) { sv = sz; cur = cz; cq = zi; }
  else                           { sv = sx; cur = cx; cq = xi; }

  // ---- bin-estimated rank -> seed window ----
  const int bq = bin_of(cq);
  const int bs = (bq > 0) ? cur[bq - 1] : 0;
  const int be = cur[bq];
  int lo = ((bs + be) >> 1) - SEED / 2;
  lo = lo < 0 ? 0 : lo;
  lo = lo > n - SEED ? n - SEED : lo;
  const float4* base = sv + lo + lane;

  // per-lane top-4 d2 (med3 chain) + eviction watermark
  float dd[CD];
  float ev = BIG;
#pragma unroll
  for (int k = 0; k < CD; ++k) dd[k] = BIG;

#define PROCD(cc, valid)                                                      \
  {                                                                           \
    const float dx = xi - (cc).x, dy = yi - (cc).y, dz = zi - (cc).z;         \
    float d2 = fmaf(dx, dx, fmaf(dy, dy, dz * dz));                           \
    d2 = (valid) ? d2 : BIG;                                                  \
    ev = fminf(ev, fmaxf(d2, dd[CD - 1]));                                    \
    dd[3] = __builtin_amdgcn_fmed3f(d2, dd[2], dd[3]);                        \
    dd[2] = __builtin_amdgcn_fmed3f(d2, dd[1], dd[2]);                        \
    dd[1] = __builtin_amdgcn_fmed3f(d2, dd[0], dd[1]);                        \
    dd[0] = fminf(dd[0], d2);                                                 \
  }

  // ---- 1. seed scan (12 chunks, grouped x4 for MLP) ----
#pragma unroll
  for (int s = 0; s < SEED / 64; s += 4) {
    const float4 c0 = base[(s + 0) * 64];
    const float4 c1 = base[(s + 1) * 64];
    const float4 c2 = base[(s + 2) * 64];
    const float4 c3 = base[(s + 3) * 64];
    PROCD(c0, true) PROCD(c1, true) PROCD(c2, true) PROCD(c3, true)
  }

  // ---- 2. u = valid UB of tau via ballot bisection (m = dd[0]) ----
  float u;
  {
    const float m = dd[0];
    float hiv = m;
#pragma unroll
    for (int o = 1; o < 64; o <<= 1) hiv = fmaxf(hiv, __shfl_xor(hiv, o));
    float lov = 0.f;
#pragma unroll
    for (int it = 0; it < 10; ++it) {
      const float mid = 0.5f * (lov + hiv);
      const int cnt = __popcll(__ballot(m <= mid));
      if (cnt >= KK) hiv = mid; else lov = mid;
    }
    u = hiv;
  }

  // ---- 3. extent from prefix sums: {|c - cq| <= sqrt(u)} ⊆ [lo2, hi2) ----
  const float s = sqrtf(u);
  const int bl = bin_of(cq - s);
  const int bh = bin_of(cq + s);
  const int lo2 = (bl > 0) ? cur[bl - 1] : 0;
  const int hi2 = cur[bh];
  const int lenE  = hi2 - lo2;
  const int steps = (lenE + 63) >> 6;

  // ---- 4. tail scans: extent minus seed window ----
  {
    const int a0 = lo2, b0 = min(hi2, lo);       // left tail
    const int len = b0 - a0;
    const int nch = (len + 63) >> 6;
    for (int c0i = 0; c0i < nch; ++c0i) {
      const int idx = c0i * 64 + lane;
      const float4 c = sv[a0 + min(idx, len - 1)];
      PROCD(c, idx < len)
    }
  }
  {
    const int a0 = max(lo2, lo + SEED), b0 = hi2; // right tail
    const int len = b0 - a0;
    const int nch = (len + 63) >> 6;
    for (int c0i = 0; c0i < nch; ++c0i) {
      const int idx = c0i * 64 + lane;
      const float4 c = sv[a0 + min(idx, len - 1)];
      PROCD(c, idx < len)
    }
  }
#undef PROCD

  // ---- 5. tau = exact 12th of scanned set (knockout, first-lane pop) ----
  float tau = 0.f;
#pragma unroll
  for (int r = 0; r < KK; ++r) {
    const float mm = wave_min(dd[0]);
    const unsigned long long bal = __ballot(dd[0] == mm);
    if (dd[0] == mm && lane == (int)(__ffsll(bal) - 1)) {
      dd[0] = dd[1]; dd[1] = dd[2]; dd[2] = dd[3]; dd[3] = BIG;
    }
    tau = mm;
  }

  // ---- 6. watermark check: rare exact rebuild over the full extent ----
  if (__ballot(ev <= tau) != 0ULL) {
    float d12[KK];
#pragma unroll
    for (int k = 0; k < KK; ++k) d12[k] = BIG;
    for (int s0 = 0; s0 < steps; ++s0) {
      const int pos = lo2 + s0 * 64 + lane;
      const float4 c = sv[(pos < hi2) ? pos : hi2 - 1];
      const float dx = xi - c.x, dy = yi - c.y, dz = zi - c.z;
      const float d2 = (pos < hi2) ? fmaf(dx, dx, fmaf(dy, dy, dz * dz)) : BIG;
#pragma unroll
      for (int k = KK - 1; k >= 1; --k)
        d12[k] = __builtin_amdgcn_fmed3f(d2, d12[k - 1], d12[k]);
      d12[0] = fminf(d12[0], d2);
    }
    tau = 0.f;
#pragma unroll
    for (int r = 0; r < KK; ++r) {
      const float mm = wave_min(d12[0]);
      if (d12[0] == mm) {
#pragma unroll
        for (int k = 0; k < KK - 1; ++k) d12[k] = d12[k + 1];
        d12[KK - 1] = BIG;
      }
      tau = mm;
    }
  }

  // ---- 7. unified rescan-accumulate over the extent (w only here) ----
  float acc = 0.f;
  for (int s0 = 0; s0 < steps; ++s0) {
    const int idx = s0 * 64 + lane;
    const float4 c = sv[lo2 + min(idx, lenE - 1)];
    const float dx = xi - c.x, dy = yi - c.y, dz = zi - c.z;
    const float d2 = fmaf(dx, dx, fmaf(dy, dy, dz * dz));
    const float w  = fmaf(W0, fabsf(dx), fmaf(W1, fabsf(dy), W2 * fabsf(dz)));
    acc += (d2 <= tau && idx < lenE) ? w : 0.f;
  }

  // ---- 8. reduce + write ----
#pragma unroll
  for (int o = 1; o < 64; o <<= 1) acc += __shfl_xor(acc, o);
  if (lane == 0) {
    const float xw0 = W0 * xi + W1 * yi + W2 * zi;
    // 1 + 11/sqrt(2)
    out[orig] = bb + (xw0 * 8.778174593052022f + 0.5f * acc) * (1.0f / 12.0f);
  }
}

extern "C" void kernel_launch(void* const* d_in, const int* in_sizes, int n_in,
                              void* d_out, int out_size, void* d_ws, size_t ws_size,
                              hipStream_t stream) {
  const float* p  = (const float*)d_in[0];
  const float* W  = (const float*)d_in[1];
  const float* bb = (const float*)d_in[2];
  float* out = (float*)d_out;

  const int n = in_sizes[0] / 3;   // 16384

  // ws layout:
  //   c_all @ 0     : 3*2048 ints  (bin ENDS, query prefix sums)
  //   s_all @ 24KB  : 3*n float4   (sorted arrays)
  int*    c_all = (int*)d_ws;
  float4* s_all = (float4*)((char*)d_ws + 3 * NBINS * 4);
  int*    cx = c_all;
  int*    cy = cx + NBINS;
  int*    cz = cy + NBINS;
  float4* sx = s_all;
  float4* sy = sx + n;
  float4* sz = sy + n;

  sort_kernel<<<3 * PARTS, 1024, 0, stream>>>(p, c_all, s_all, n);
  query_kernel<<<n / WPB, BLOCK, 0, stream>>>(sx, sy, sz, cx, cy, cz, W, bb, out, n);
}

// Round 10
// 105.803 us; speedup vs baseline: 1.0367x; 1.0367x over previous
//
#include <hip/hip_runtime.h>
#include <math.h>

// n=16384 Gaussian points in 3D. Exact 12-NN (incl self) per point:
//   out[i] = b + ( (W·p_i)·(1 + 11/sqrt(2)) + 0.5 * sum_{11NN} W·|p_i - p_j| ) / 12
//
// R24: two latency exposures attacked (R23: VALUBusy 62%, occ 43%):
//   1. ADJACENT-rank wave mapping (t = blockIdx*4 + wv, was quartile
//      interleave): a block's 4 waves now read ~99%-overlapping seed/extent
//      windows -> L1 line sharing across co-resident waves. Grid-level
//      balance via 4096 blocks >> 256 CUs.
//   2. tau via 24-iter ballot BISECTION over the 4 per-lane regs on [0,u]
//      (dep chain ~10cy/iter, no DS pipe) replacing the 12-round knockout
//      (~2400cy serial ds_swizzle). Exactness: accept only if
//      cnt(d2<=tau)==12 over dd AND no watermark violation; else fall back
//      to the exact knockout (+ full-extent rebuild if ev<=tau) — identical
//      semantics to R23. (cnt==12 + ev>tau guarantees the rescan sums
//      exactly the 12 winners; any evicted candidate <=tau implies ev<=tau.)
// Rest unchanged from R23: d2-only med3 selection, u from 10-iter seed
// bisection, unified rescan-accumulate. Sort unchanged (R18).

#define NBINS  2048
#define PARTS  16
#define CMIN_  (-6.0f)
#define INVBW_ ((float)NBINS / 12.0f)
#define BLOCK  256
#define WPB    4
#define SEED   768
#define KK     12
#define CD     4
#define BIG    3.0e38f

__device__ __forceinline__ int bin_of(float x) {
  int b = (int)((x - CMIN_) * INVBW_);
  b = b < 0 ? 0 : b;
  b = b > NBINS - 1 ? NBINS - 1 : b;
  return b;
}

__device__ __forceinline__ float wave_min(float v) {
#pragma unroll
  for (int o = 1; o < 64; o <<= 1) v = fminf(v, __shfl_xor(v, o));
  return v;
}

// ---------------- K1: self-sufficient fused sort (grid = 3*PARTS, plain) ----
__global__ __launch_bounds__(1024)
void sort_kernel(const float* __restrict__ p, int* __restrict__ c_all,
                 float4* __restrict__ s_all, int n) {
  __shared__ int h_all[NBINS];   // full per-axis histogram
  __shared__ int h_pre[NBINS];   // hist of indices < myStart; later: cursors
  __shared__ int wsum[16];
  const int tid  = threadIdx.x;
  const int dim  = blockIdx.x / PARTS;
  const int part = blockIdx.x % PARTS;
  const int chunk   = (n + PARTS - 1) / PARTS;
  const int myStart = part * chunk;
  const int myEnd   = min(myStart + chunk, n);

  h_all[tid] = 0; h_all[tid + 1024] = 0;
  h_pre[tid] = 0; h_pre[tid + 1024] = 0;
  __syncthreads();

  for (int i = tid; i < n; i += 1024) {
    const int b = bin_of(p[3 * i + dim]);
    atomicAdd(&h_all[b], 1);
    if (i < myStart) atomicAdd(&h_pre[b], 1);   // wave-uniform predicate
  }
  __syncthreads();

  const int a = h_all[2 * tid], b = h_all[2 * tid + 1];
  const int v = a + b;
  const int lane = tid & 63, wid = tid >> 6;     // 16 waves
  int incl = v;
#pragma unroll
  for (int o = 1; o < 64; o <<= 1) {
    const int t = __shfl_up(incl, o);
    if (lane >= o) incl += t;
  }
  if (lane == 63) wsum[wid] = incl;
  __syncthreads();
  int woff = 0;
  for (int wI = 0; wI < wid; ++wI) woff += wsum[wI];   // broadcast reads
  const int excl = woff + incl - v;                    // start of bin 2*tid

  if (part == 0) {
    int* __restrict__ cursor = c_all + (size_t)dim * NBINS;
    cursor[2 * tid]     = excl + a;
    cursor[2 * tid + 1] = excl + a + b;
  }

  const int c0 = excl + h_pre[2 * tid];
  const int c1 = excl + a + h_pre[2 * tid + 1];
  __syncthreads();
  h_pre[2 * tid]     = c0;
  h_pre[2 * tid + 1] = c1;
  __syncthreads();

  float4* __restrict__ sorted = s_all + (size_t)dim * n;
  for (int i = myStart + tid; i < myEnd; i += 1024) {
    const float x = p[3 * i], y = p[3 * i + 1], z = p[3 * i + 2];
    const float c = (dim == 0) ? x : (dim == 1) ? y : z;
    const int pos = atomicAdd(&h_pre[bin_of(c)], 1);
    sorted[pos] = make_float4(x, y, z, __int_as_float(i));
  }
}

// ---------------- K2: query (one wave per query, d2-select + rescan) --------
__global__ __launch_bounds__(BLOCK, 1)
void query_kernel(const float4* __restrict__ sx, const float4* __restrict__ sy,
                  const float4* __restrict__ sz, const int* __restrict__ cx,
                  const int* __restrict__ cy, const int* __restrict__ cz,
                  const float* __restrict__ W, const float* __restrict__ bias,
                  float* __restrict__ out, int n) {
  const int lane = threadIdx.x & 63;
  const int wv   = threadIdx.x >> 6;
  const int t    = blockIdx.x * WPB + wv;   // ADJACENT ranks: L1 sharing
  const float W0 = W[0], W1 = W[1], W2 = W[2];
  const float bb = bias[0];

  const float4 me = sx[t];                          // enumerate via x-sorted
  const float xi = me.x, yi = me.y, zi = me.z;
  const int orig = __float_as_int(me.w);

  // ---- choose axis with max |coord| (wave-uniform) ----
  const float ax = fabsf(xi), ay = fabsf(yi), az = fabsf(zi);
  const float4* sv; const int* cur; float cq;
  if (ay >= ax && ay >= az)      { sv = sy; cur = cy; cq = yi; }
  else if (az >= ax && az >= ay) { sv = sz; cur = cz; cq = zi; }
  else                           { sv = sx; cur = cx; cq = xi; }

  // ---- bin-estimated rank -> seed window ----
  const int bq = bin_of(cq);
  const int bs = (bq > 0) ? cur[bq - 1] : 0;
  const int be = cur[bq];
  int lo = ((bs + be) >> 1) - SEED / 2;
  lo = lo < 0 ? 0 : lo;
  lo = lo > n - SEED ? n - SEED : lo;
  const float4* base = sv + lo + lane;

  // per-lane top-4 d2 (med3 chain) + eviction watermark
  float dd[CD];
  float ev = BIG;
#pragma unroll
  for (int k = 0; k < CD; ++k) dd[k] = BIG;

#define PROCD(cc, valid)                                                      \
  {                                                                           \
    const float dx = xi - (cc).x, dy = yi - (cc).y, dz = zi - (cc).z;         \
    float d2 = fmaf(dx, dx, fmaf(dy, dy, dz * dz));                           \
    d2 = (valid) ? d2 : BIG;                                                  \
    ev = fminf(ev, fmaxf(d2, dd[CD - 1]));                                    \
    dd[3] = __builtin_amdgcn_fmed3f(d2, dd[2], dd[3]);                        \
    dd[2] = __builtin_amdgcn_fmed3f(d2, dd[1], dd[2]);                        \
    dd[1] = __builtin_amdgcn_fmed3f(d2, dd[0], dd[1]);                        \
    dd[0] = fminf(dd[0], d2);                                                 \
  }

  // ---- 1. seed scan (12 chunks, grouped x4 for MLP) ----
#pragma unroll
  for (int s = 0; s < SEED / 64; s += 4) {
    const float4 c0 = base[(s + 0) * 64];
    const float4 c1 = base[(s + 1) * 64];
    const float4 c2 = base[(s + 2) * 64];
    const float4 c3 = base[(s + 3) * 64];
    PROCD(c0, true) PROCD(c1, true) PROCD(c2, true) PROCD(c3, true)
  }

  // ---- 2. u = valid UB of tau via ballot bisection (m = dd[0]) ----
  float u;
  {
    const float m = dd[0];
    float hiv = m;
#pragma unroll
    for (int o = 1; o < 64; o <<= 1) hiv = fmaxf(hiv, __shfl_xor(hiv, o));
    float lov = 0.f;
#pragma unroll
    for (int it = 0; it < 10; ++it) {
      const float mid = 0.5f * (lov + hiv);
      const int cnt = __popcll(__ballot(m <= mid));
      if (cnt >= KK) hiv = mid; else lov = mid;
    }
    u = hiv;
  }

  // ---- 3. extent from prefix sums: {|c - cq| <= sqrt(u)} ⊆ [lo2, hi2) ----
  const float s = sqrtf(u);
  const int bl = bin_of(cq - s);
  const int bh = bin_of(cq + s);
  const int lo2 = (bl > 0) ? cur[bl - 1] : 0;
  const int hi2 = cur[bh];
  const int lenE  = hi2 - lo2;
  const int steps = (lenE + 63) >> 6;

  // ---- 4. tail scans: extent minus seed window ----
  {
    const int a0 = lo2, b0 = min(hi2, lo);       // left tail
    const int len = b0 - a0;
    const int nch = (len + 63) >> 6;
    for (int c0i = 0; c0i < nch; ++c0i) {
      const int idx = c0i * 64 + lane;
      const float4 c = sv[a0 + min(idx, len - 1)];
      PROCD(c, idx < len)
    }
  }
  {
    const int a0 = max(lo2, lo + SEED), b0 = hi2; // right tail
    const int len = b0 - a0;
    const int nch = (len + 63) >> 6;
    for (int c0i = 0; c0i < nch; ++c0i) {
      const int idx = c0i * 64 + lane;
      const float4 c = sv[a0 + min(idx, len - 1)];
      PROCD(c, idx < len)
    }
  }
#undef PROCD

  // ---- 5. tau via 24-iter ballot bisection over dd on [0, u] ----
  float tau;
  {
    float hiv = u, lov = 0.f;
#pragma unroll
    for (int it = 0; it < 24; ++it) {
      const float mid = 0.5f * (lov + hiv);
      const int cnt = __popcll(__ballot(dd[0] <= mid)) +
                      __popcll(__ballot(dd[1] <= mid)) +
                      __popcll(__ballot(dd[2] <= mid)) +
                      __popcll(__ballot(dd[3] <= mid));
      if (cnt >= KK) hiv = mid; else lov = mid;
    }
    tau = hiv;
  }
  {
    const int cntF = __popcll(__ballot(dd[0] <= tau)) +
                     __popcll(__ballot(dd[1] <= tau)) +
                     __popcll(__ballot(dd[2] <= tau)) +
                     __popcll(__ballot(dd[3] <= tau));
    const bool bad = (cntF != KK) || (__ballot(ev <= tau) != 0ULL);
    if (bad) {                      // wave-uniform, rare
      // exact 12th of dd via knockout
      tau = 0.f;
#pragma unroll
      for (int r = 0; r < KK; ++r) {
        const float mm = wave_min(dd[0]);
        const unsigned long long bal = __ballot(dd[0] == mm);
        if (dd[0] == mm && lane == (int)(__ffsll(bal) - 1)) {
          dd[0] = dd[1]; dd[1] = dd[2]; dd[2] = dd[3]; dd[3] = BIG;
        }
        tau = mm;
      }
      if (__ballot(ev <= tau) != 0ULL) {
        // full-extent exact rebuild (12-deep med3 + knockout)
        float d12[KK];
#pragma unroll
        for (int k = 0; k < KK; ++k) d12[k] = BIG;
        for (int s0 = 0; s0 < steps; ++s0) {
          const int pos = lo2 + s0 * 64 + lane;
          const float4 c = sv[(pos < hi2) ? pos : hi2 - 1];
          const float dx = xi - c.x, dy = yi - c.y, dz = zi - c.z;
          const float d2 = (pos < hi2) ? fmaf(dx, dx, fmaf(dy, dy, dz * dz)) : BIG;
#pragma unroll
          for (int k = KK - 1; k >= 1; --k)
            d12[k] = __builtin_amdgcn_fmed3f(d2, d12[k - 1], d12[k]);
          d12[0] = fminf(d12[0], d2);
        }
        tau = 0.f;
#pragma unroll
        for (int r = 0; r < KK; ++r) {
          const float mm = wave_min(d12[0]);
          if (d12[0] == mm) {
#pragma unroll
            for (int k = 0; k < KK - 1; ++k) d12[k] = d12[k + 1];
            d12[KK - 1] = BIG;
          }
          tau = mm;
        }
      }
    }
  }

  // ---- 6. unified rescan-accumulate over the extent (w only here) ----
  float acc = 0.f;
  for (int s0 = 0; s0 < steps; ++s0) {
    const int idx = s0 * 64 + lane;
    const float4 c = sv[lo2 + min(idx, lenE - 1)];
    const float dx = xi - c.x, dy = yi - c.y, dz = zi - c.z;
    const float d2 = fmaf(dx, dx, fmaf(dy, dy, dz * dz));
    const float w  = fmaf(W0, fabsf(dx), fmaf(W1, fabsf(dy), W2 * fabsf(dz)));
    acc += (d2 <= tau && idx < lenE) ? w : 0.f;
  }

  // ---- 7. reduce + write ----
#pragma unroll
  for (int o = 1; o < 64; o <<= 1) acc += __shfl_xor(acc, o);
  if (lane == 0) {
    const float xw0 = W0 * xi + W1 * yi + W2 * zi;
    // 1 + 11/sqrt(2)
    out[orig] = bb + (xw0 * 8.778174593052022f + 0.5f * acc) * (1.0f / 12.0f);
  }
}

extern "C" void kernel_launch(void* const* d_in, const int* in_sizes, int n_in,
                              void* d_out, int out_size, void* d_ws, size_t ws_size,
                              hipStream_t stream) {
  const float* p  = (const float*)d_in[0];
  const float* W  = (const float*)d_in[1];
  const float* bb = (const float*)d_in[2];
  float* out = (float*)d_out;

  const int n = in_sizes[0] / 3;   // 16384

  // ws layout:
  //   c_all @ 0     : 3*2048 ints  (bin ENDS, query prefix sums)
  //   s_all @ 24KB  : 3*n float4   (sorted arrays)
  int*    c_all = (int*)d_ws;
  float4* s_all = (float4*)((char*)d_ws + 3 * NBINS * 4);
  int*    cx = c_all;
  int*    cy = cx + NBINS;
  int*    cz = cy + NBINS;
  float4* sx = s_all;
  float4* sy = sx + n;
  float4* sz = sy + n;

  sort_kernel<<<3 * PARTS, 1024, 0, stream>>>(p, c_all, s_all, n);
  query_kernel<<<n / WPB, BLOCK, 0, stream>>>(sx, sy, sz, cx, cy, cz, W, bb, out, n);
}

// Round 11
// 101.704 us; speedup vs baseline: 1.0785x; 1.0403x over previous
//
#include <hip/hip_runtime.h>
#include <math.h>

// n=16384 Gaussian points in 3D. Exact 12-NN (incl self) per point:
//   out[i] = b + ( (W·p_i)·(1 + 11/sqrt(2)) + 0.5 * sum_{11NN} W·|p_i - p_j| ) / 12
//
// R25: rescan-accumulate now iterates the TAU-slab, not the u-extent.
// After tau (exact 12th distance) is known, every winner satisfies
// |c - cq| <= sqrt(tau) -> extent from the same prefix sums is
// ~sqrt(tau/u) narrower (~5 chunks vs ~13). Deletes ~8 of ~27 load
// batches/query. Both tau paths (bisection-accepted and fallback-rebuilt)
// satisfy tau-slab ⊇ {d2<=tau}; clamp guard kept against double-count.
// R24 carried: adjacent-rank wave mapping (L1 sharing), tau via 24-iter
// ballot bisection over the 4 per-lane regs (watermark + count guard,
// exact-knockout fallback). R23 carried: d2-only med3 selection, unified
// rescan. Sort unchanged (R18: one self-sufficient plain dispatch).

#define NBINS  2048
#define PARTS  16
#define CMIN_  (-6.0f)
#define INVBW_ ((float)NBINS / 12.0f)
#define BLOCK  256
#define WPB    4
#define SEED   768
#define KK     12
#define CD     4
#define BIG    3.0e38f

__device__ __forceinline__ int bin_of(float x) {
  int b = (int)((x - CMIN_) * INVBW_);
  b = b < 0 ? 0 : b;
  b = b > NBINS - 1 ? NBINS - 1 : b;
  return b;
}

__device__ __forceinline__ float wave_min(float v) {
#pragma unroll
  for (int o = 1; o < 64; o <<= 1) v = fminf(v, __shfl_xor(v, o));
  return v;
}

// ---------------- K1: self-sufficient fused sort (grid = 3*PARTS, plain) ----
__global__ __launch_bounds__(1024)
void sort_kernel(const float* __restrict__ p, int* __restrict__ c_all,
                 float4* __restrict__ s_all, int n) {
  __shared__ int h_all[NBINS];   // full per-axis histogram
  __shared__ int h_pre[NBINS];   // hist of indices < myStart; later: cursors
  __shared__ int wsum[16];
  const int tid  = threadIdx.x;
  const int dim  = blockIdx.x / PARTS;
  const int part = blockIdx.x % PARTS;
  const int chunk   = (n + PARTS - 1) / PARTS;
  const int myStart = part * chunk;
  const int myEnd   = min(myStart + chunk, n);

  h_all[tid] = 0; h_all[tid + 1024] = 0;
  h_pre[tid] = 0; h_pre[tid + 1024] = 0;
  __syncthreads();

  for (int i = tid; i < n; i += 1024) {
    const int b = bin_of(p[3 * i + dim]);
    atomicAdd(&h_all[b], 1);
    if (i < myStart) atomicAdd(&h_pre[b], 1);   // wave-uniform predicate
  }
  __syncthreads();

  const int a = h_all[2 * tid], b = h_all[2 * tid + 1];
  const int v = a + b;
  const int lane = tid & 63, wid = tid >> 6;     // 16 waves
  int incl = v;
#pragma unroll
  for (int o = 1; o < 64; o <<= 1) {
    const int t = __shfl_up(incl, o);
    if (lane >= o) incl += t;
  }
  if (lane == 63) wsum[wid] = incl;
  __syncthreads();
  int woff = 0;
  for (int wI = 0; wI < wid; ++wI) woff += wsum[wI];   // broadcast reads
  const int excl = woff + incl - v;                    // start of bin 2*tid

  if (part == 0) {
    int* __restrict__ cursor = c_all + (size_t)dim * NBINS;
    cursor[2 * tid]     = excl + a;
    cursor[2 * tid + 1] = excl + a + b;
  }

  const int c0 = excl + h_pre[2 * tid];
  const int c1 = excl + a + h_pre[2 * tid + 1];
  __syncthreads();
  h_pre[2 * tid]     = c0;
  h_pre[2 * tid + 1] = c1;
  __syncthreads();

  float4* __restrict__ sorted = s_all + (size_t)dim * n;
  for (int i = myStart + tid; i < myEnd; i += 1024) {
    const float x = p[3 * i], y = p[3 * i + 1], z = p[3 * i + 2];
    const float c = (dim == 0) ? x : (dim == 1) ? y : z;
    const int pos = atomicAdd(&h_pre[bin_of(c)], 1);
    sorted[pos] = make_float4(x, y, z, __int_as_float(i));
  }
}

// ---------------- K2: query (one wave per query, d2-select + tau-rescan) ----
__global__ __launch_bounds__(BLOCK, 1)
void query_kernel(const float4* __restrict__ sx, const float4* __restrict__ sy,
                  const float4* __restrict__ sz, const int* __restrict__ cx,
                  const int* __restrict__ cy, const int* __restrict__ cz,
                  const float* __restrict__ W, const float* __restrict__ bias,
                  float* __restrict__ out, int n) {
  const int lane = threadIdx.x & 63;
  const int wv   = threadIdx.x >> 6;
  const int t    = blockIdx.x * WPB + wv;   // ADJACENT ranks: L1 sharing
  const float W0 = W[0], W1 = W[1], W2 = W[2];
  const float bb = bias[0];

  const float4 me = sx[t];                          // enumerate via x-sorted
  const float xi = me.x, yi = me.y, zi = me.z;
  const int orig = __float_as_int(me.w);

  // ---- choose axis with max |coord| (wave-uniform) ----
  const float ax = fabsf(xi), ay = fabsf(yi), az = fabsf(zi);
  const float4* sv; const int* cur; float cq;
  if (ay >= ax && ay >= az)      { sv = sy; cur = cy; cq = yi; }
  else if (az >= ax && az >= ay) { sv = sz; cur = cz; cq = zi; }
  else                           { sv = sx; cur = cx; cq = xi; }

  // ---- bin-estimated rank -> seed window ----
  const int bq = bin_of(cq);
  const int bs = (bq > 0) ? cur[bq - 1] : 0;
  const int be = cur[bq];
  int lo = ((bs + be) >> 1) - SEED / 2;
  lo = lo < 0 ? 0 : lo;
  lo = lo > n - SEED ? n - SEED : lo;
  const float4* base = sv + lo + lane;

  // per-lane top-4 d2 (med3 chain) + eviction watermark
  float dd[CD];
  float ev = BIG;
#pragma unroll
  for (int k = 0; k < CD; ++k) dd[k] = BIG;

#define PROCD(cc, valid)                                                      \
  {                                                                           \
    const float dx = xi - (cc).x, dy = yi - (cc).y, dz = zi - (cc).z;         \
    float d2 = fmaf(dx, dx, fmaf(dy, dy, dz * dz));                           \
    d2 = (valid) ? d2 : BIG;                                                  \
    ev = fminf(ev, fmaxf(d2, dd[CD - 1]));                                    \
    dd[3] = __builtin_amdgcn_fmed3f(d2, dd[2], dd[3]);                        \
    dd[2] = __builtin_amdgcn_fmed3f(d2, dd[1], dd[2]);                        \
    dd[1] = __builtin_amdgcn_fmed3f(d2, dd[0], dd[1]);                        \
    dd[0] = fminf(dd[0], d2);                                                 \
  }

  // ---- 1. seed scan (12 chunks, grouped x4 for MLP) ----
#pragma unroll
  for (int s = 0; s < SEED / 64; s += 4) {
    const float4 c0 = base[(s + 0) * 64];
    const float4 c1 = base[(s + 1) * 64];
    const float4 c2 = base[(s + 2) * 64];
    const float4 c3 = base[(s + 3) * 64];
    PROCD(c0, true) PROCD(c1, true) PROCD(c2, true) PROCD(c3, true)
  }

  // ---- 2. u = valid UB of tau via ballot bisection (m = dd[0]) ----
  float u;
  {
    const float m = dd[0];
    float hiv = m;
#pragma unroll
    for (int o = 1; o < 64; o <<= 1) hiv = fmaxf(hiv, __shfl_xor(hiv, o));
    float lov = 0.f;
#pragma unroll
    for (int it = 0; it < 10; ++it) {
      const float mid = 0.5f * (lov + hiv);
      const int cnt = __popcll(__ballot(m <= mid));
      if (cnt >= KK) hiv = mid; else lov = mid;
    }
    u = hiv;
  }

  // ---- 3. extent from prefix sums: {|c - cq| <= sqrt(u)} ⊆ [lo2, hi2) ----
  const float s = sqrtf(u);
  const int bl = bin_of(cq - s);
  const int bh = bin_of(cq + s);
  const int lo2 = (bl > 0) ? cur[bl - 1] : 0;
  const int hi2 = cur[bh];
  const int steps = (hi2 - lo2 + 63) >> 6;

  // ---- 4. tail scans: extent minus seed window ----
  {
    const int a0 = lo2, b0 = min(hi2, lo);       // left tail
    const int len = b0 - a0;
    const int nch = (len + 63) >> 6;
    for (int c0i = 0; c0i < nch; ++c0i) {
      const int idx = c0i * 64 + lane;
      const float4 c = sv[a0 + min(idx, len - 1)];
      PROCD(c, idx < len)
    }
  }
  {
    const int a0 = max(lo2, lo + SEED), b0 = hi2; // right tail
    const int len = b0 - a0;
    const int nch = (len + 63) >> 6;
    for (int c0i = 0; c0i < nch; ++c0i) {
      const int idx = c0i * 64 + lane;
      const float4 c = sv[a0 + min(idx, len - 1)];
      PROCD(c, idx < len)
    }
  }
#undef PROCD

  // ---- 5. tau via 24-iter ballot bisection over dd on [0, u] ----
  float tau;
  {
    float hiv = u, lov = 0.f;
#pragma unroll
    for (int it = 0; it < 24; ++it) {
      const float mid = 0.5f * (lov + hiv);
      const int cnt = __popcll(__ballot(dd[0] <= mid)) +
                      __popcll(__ballot(dd[1] <= mid)) +
                      __popcll(__ballot(dd[2] <= mid)) +
                      __popcll(__ballot(dd[3] <= mid));
      if (cnt >= KK) hiv = mid; else lov = mid;
    }
    tau = hiv;
  }
  {
    const int cntF = __popcll(__ballot(dd[0] <= tau)) +
                     __popcll(__ballot(dd[1] <= tau)) +
                     __popcll(__ballot(dd[2] <= tau)) +
                     __popcll(__ballot(dd[3] <= tau));
    const bool bad = (cntF != KK) || (__ballot(ev <= tau) != 0ULL);
    if (bad) {                      // wave-uniform, rare
      // exact 12th of dd via knockout
      tau = 0.f;
#pragma unroll
      for (int r = 0; r < KK; ++r) {
        const float mm = wave_min(dd[0]);
        const unsigned long long bal = __ballot(dd[0] == mm);
        if (dd[0] == mm && lane == (int)(__ffsll(bal) - 1)) {
          dd[0] = dd[1]; dd[1] = dd[2]; dd[2] = dd[3]; dd[3] = BIG;
        }
        tau = mm;
      }
      if (__ballot(ev <= tau) != 0ULL) {
        // full-extent exact rebuild (12-deep med3 + knockout)
        float d12[KK];
#pragma unroll
        for (int k = 0; k < KK; ++k) d12[k] = BIG;
        for (int s0 = 0; s0 < steps; ++s0) {
          const int pos = lo2 + s0 * 64 + lane;
          const float4 c = sv[(pos < hi2) ? pos : hi2 - 1];
          const float dx = xi - c.x, dy = yi - c.y, dz = zi - c.z;
          const float d2 = (pos < hi2) ? fmaf(dx, dx, fmaf(dy, dy, dz * dz)) : BIG;
#pragma unroll
          for (int k = KK - 1; k >= 1; --k)
            d12[k] = __builtin_amdgcn_fmed3f(d2, d12[k - 1], d12[k]);
          d12[0] = fminf(d12[0], d2);
        }
        tau = 0.f;
#pragma unroll
        for (int r = 0; r < KK; ++r) {
          const float mm = wave_min(d12[0]);
          if (d12[0] == mm) {
#pragma unroll
            for (int k = 0; k < KK - 1; ++k) d12[k] = d12[k + 1];
            d12[KK - 1] = BIG;
          }
          tau = mm;
        }
      }
    }
  }

  // ---- 6. rescan-accumulate over the TAU-slab (w only here) ----
  // winners satisfy |c - cq| <= sqrt(tau) -> much narrower than u-extent
  float acc = 0.f;
  {
    const float s3 = sqrtf(tau);
    const int bl3 = bin_of(cq - s3);
    const int bh3 = bin_of(cq + s3);
    const int lo3 = (bl3 > 0) ? cur[bl3 - 1] : 0;
    const int hi3 = cur[bh3];
    const int len3 = hi3 - lo3;
    const int nch3 = (len3 + 63) >> 6;
    for (int s0 = 0; s0 < nch3; ++s0) {
      const int idx = s0 * 64 + lane;
      const float4 c = sv[lo3 + min(idx, len3 - 1)];
      const float dx = xi - c.x, dy = yi - c.y, dz = zi - c.z;
      const float d2 = fmaf(dx, dx, fmaf(dy, dy, dz * dz));
      const float w  = fmaf(W0, fabsf(dx), fmaf(W1, fabsf(dy), W2 * fabsf(dz)));
      acc += (d2 <= tau && idx < len3) ? w : 0.f;
    }
  }

  // ---- 7. reduce + write ----
#pragma unroll
  for (int o = 1; o < 64; o <<= 1) acc += __shfl_xor(acc, o);
  if (lane == 0) {
    const float xw0 = W0 * xi + W1 * yi + W2 * zi;
    // 1 + 11/sqrt(2)
    out[orig] = bb + (xw0 * 8.778174593052022f + 0.5f * acc) * (1.0f / 12.0f);
  }
}

extern "C" void kernel_launch(void* const* d_in, const int* in_sizes, int n_in,
                              void* d_out, int out_size, void* d_ws, size_t ws_size,
                              hipStream_t stream) {
  const float* p  = (const float*)d_in[0];
  const float* W  = (const float*)d_in[1];
  const float* bb = (const float*)d_in[2];
  float* out = (float*)d_out;

  const int n = in_sizes[0] / 3;   // 16384

  // ws layout:
  //   c_all @ 0     : 3*2048 ints  (bin ENDS, query prefix sums)
  //   s_all @ 24KB  : 3*n float4   (sorted arrays)
  int*    c_all = (int*)d_ws;
  float4* s_all = (float4*)((char*)d_ws + 3 * NBINS * 4);
  int*    cx = c_all;
  int*    cy = cx + NBINS;
  int*    cz = cy + NBINS;
  float4* sx = s_all;
  float4* sy = sx + n;
  float4* sz = sy + n;

  sort_kernel<<<3 * PARTS, 1024, 0, stream>>>(p, c_all, s_all, n);
  query_kernel<<<n / WPB, BLOCK, 0, stream>>>(sx, sy, sz, cx, cy, cz, W, bb, out, n);
}